// Round 12
// baseline (261.278 us; speedup 1.0000x reference)
//
#include <hip/hip_runtime.h>
#include <stdint.h>

namespace {

typedef __attribute__((ext_vector_type(8)))  short short8;   // 8 bf16
typedef __attribute__((ext_vector_type(16))) float f32x16;
typedef __attribute__((ext_vector_type(4)))  float f32x4;

union U4 {
    uint4    q;
    uint32_t u[4];
    uint16_t us[8];
    short8   s8;
};

constexpr float INV_SCALE = 0.08838834764831845f;  // 1/sqrt(128), BOTH attn blocks

// ---- workspace (weight fragment) layout, bytes (prepack UNCHANGED) ----
constexpr size_t WSPROJ = 65536;            // 4c*8kb*2(hi,lo)*1024
constexpr size_t WP1OFF = 6 * WSPROJ;       // Wp1: c=0..7, kb=0..7 -> 131072 B
constexpr size_t WP2OFF = WP1OFF + 131072;  // Wp2 (16x16 frags): kb=0..7 -> 16384 B

// ---- LDS arena: 65536 B, TWO batches row-stacked (64 rows), 2 blocks/CU ----
constexpr int AH_OFF = 0;       // X/WAV/NF hi plane bf16 [64][128], swizzled, 16KB
constexpr int AL_OFF = 16384;   // X/WAV/NF lo plane 16KB; Q plane ALIASES (X-lo dead post-proj)
constexpr int KB_OFF = 32768;   // K plane bf16 [64][128] 16KB; S fp32 [64][36dw] aliases post-S-read
constexpr int VT_OFF = 49152;   // V 1-term RNE plane [128 e][64 m] bf16, swizzled, 16KB
// H bf16 [64][256] (32KB) aliases KB+VT at MLP time; policy logits alias AH.

__device__ __forceinline__ int pl_addr(int base, int n, int e) {   // bf16 plane [64][128]
    return base + ((n * 256 + e * 2) ^ ((n & 15) << 4));
}
__device__ __forceinline__ int vt_addr(int e, int m) {             // bf16 [128][64]
    return VT_OFF + ((e * 128 + m * 2) ^ ((e & 7) << 4));
}
__device__ __forceinline__ int s_addr(int n, int m) {              // fp32 [64][36dw], over KB
    return KB_OFF + n * 144 + m * 4;
}
__device__ __forceinline__ int h_addr(int n, int h) {              // bf16 [64][256], over KB+VT
    return KB_OFF + ((n * 512 + h * 2) ^ ((n & 15) << 4));
}
__device__ __forceinline__ int ps_addr(int n, int a) {             // fp32 [64][36dw], over AH
    return AH_OFF + n * 144 + a * 4;
}

__device__ __forceinline__ uint16_t f2bf_rne(float x) {
    uint32_t u = __float_as_uint(x);
    u += 0x7FFFu + ((u >> 16) & 1u);
    return (uint16_t)(u >> 16);
}

// split 8 fp32 -> (hi bf16x8, lo bf16x8); hi = trunc, lo = trunc(x - hi)
__device__ __forceinline__ void split8(float4 a, float4 b, short8& hi, short8& lo) {
    float xs[8] = {a.x, a.y, a.z, a.w, b.x, b.y, b.z, b.w};
    U4 h, l;
#pragma unroll
    for (int p = 0; p < 4; ++p) {
        uint32_t b0 = __float_as_uint(xs[2 * p]);
        uint32_t b1 = __float_as_uint(xs[2 * p + 1]);
        float r0 = xs[2 * p]     - __uint_as_float(b0 & 0xFFFF0000u);
        float r1 = xs[2 * p + 1] - __uint_as_float(b1 & 0xFFFF0000u);
        h.u[p] = __builtin_amdgcn_perm(b1, b0, 0x07060302u);
        l.u[p] = __builtin_amdgcn_perm(__float_as_uint(r1), __float_as_uint(r0), 0x07060302u);
    }
    hi = h.s8; lo = l.s8;
}

// 32-row GEMM tile (rows rowoff..rowoff+31, col-tile c, K=128), 3-term split.
// Single accumulator per wave -> ~85 live regs, fits the (512,4) 128-reg cap.
__device__ __forceinline__ f32x16 gemm32r(const char* smem, const uint8_t* __restrict__ matbase,
                                          int rowoff, int c, int l) {
    f32x16 acc = {0.f,0.f,0.f,0.f, 0.f,0.f,0.f,0.f, 0.f,0.f,0.f,0.f, 0.f,0.f,0.f,0.f};
    const int n = rowoff + (l & 31), half = l >> 5;
#pragma unroll 2
    for (int kb = 0; kb < 8; ++kb) {
        const int d0 = kb * 16 + half * 8;
        U4 ah, al;
        ah.q = *(const uint4*)(smem + pl_addr(AH_OFF, n, d0));
        al.q = *(const uint4*)(smem + pl_addr(AL_OFF, n, d0));
        const uint8_t* p = matbase + (size_t)((c * 8 + kb) * 2) * 1024 + (size_t)l * 16;
        U4 bh, bl;
        bh.q = *(const uint4*)p;
        bl.q = *(const uint4*)(p + 1024);
        acc = __builtin_amdgcn_mfma_f32_32x32x16_bf16(ah.s8, bh.s8, acc, 0, 0, 0);
        acc = __builtin_amdgcn_mfma_f32_32x32x16_bf16(al.s8, bh.s8, acc, 0, 0, 0);
        acc = __builtin_amdgcn_mfma_f32_32x32x16_bf16(ah.s8, bl.s8, acc, 0, 0, 0);
    }
    return acc;
}

// store 32x32 D-tile as 1-term RNE bf16 plane at row offset
__device__ __forceinline__ void store_plane32(char* smem, int base, int rowoff, int c, int l,
                                              const f32x16& a) {
    const int e = c * 32 + (l & 31);
    const int half = l >> 5;
#pragma unroll
    for (int r = 0; r < 16; ++r) {
        int n = rowoff + (r & 3) + 8 * (r >> 2) + 4 * half;   // verified 32x32 D mapping
        *(uint16_t*)(smem + pl_addr(base, n, e)) = f2bf_rne(a[r]);
    }
}

// store 32x32 D-tile as hi/lo trunc-split ACT planes at row offset
__device__ __forceinline__ void store_act32(char* smem, int rowoff, int c, int l, const f32x16& a) {
    const int e = c * 32 + (l & 31);
    const int half = l >> 5;
#pragma unroll
    for (int r = 0; r < 16; ++r) {
        int n = rowoff + (r & 3) + 8 * (r >> 2) + 4 * half;
        uint32_t bu = __float_as_uint(a[r]);
        float rr = a[r] - __uint_as_float(bu & 0xFFFF0000u);
        *(uint16_t*)(smem + pl_addr(AH_OFF, n, e)) = (uint16_t)(bu >> 16);
        *(uint16_t*)(smem + pl_addr(AL_OFF, n, e)) = (uint16_t)(__float_as_uint(rr) >> 16);
    }
}

// -------- pre-pass: convert weights to fragment-ordered split-bf16 in d_ws --------
__global__ void prepack(const float* __restrict__ Wk1, const float* __restrict__ Wq1,
                        const float* __restrict__ Wv1, const float* __restrict__ Wk2,
                        const float* __restrict__ Wq2, const float* __restrict__ Wv2,
                        const float* __restrict__ Wp1, const float* __restrict__ Wp2,
                        uint8_t* __restrict__ wsb) {
    const int bid = blockIdx.x;
    const int l = threadIdx.x;
    float4 fa = make_float4(0.f, 0.f, 0.f, 0.f), fb = fa;
    uint8_t* dst;
    if (bid < 192) {                       // 6 proj matrices, 32x32 B-frags
        int m = bid >> 5, rem = bid & 31, c = rem >> 3, kb = rem & 7;
        const float* W = (m == 0) ? Wk1 : (m == 1) ? Wq1 : (m == 2) ? Wv1
                       : (m == 3) ? Wk2 : (m == 4) ? Wq2 : Wv2;
        int e  = c * 32 + (l & 31);
        int d0 = kb * 16 + (l >> 5) * 8;
        const float* src = W + e * 128 + d0;
        fa = *(const float4*)src;
        fb = *(const float4*)(src + 4);
        dst = wsb + (size_t)m * WSPROJ + (size_t)((c * 8 + kb) * 2) * 1024 + l * 16;
    } else if (bid < 256) {                // Wp1 [256][128]
        int idx = bid - 192, c = idx >> 3, kb = idx & 7;
        int e  = c * 32 + (l & 31);
        int d0 = kb * 16 + (l >> 5) * 8;
        const float* src = Wp1 + e * 128 + d0;
        fa = *(const float4*)src;
        fb = *(const float4*)(src + 4);
        dst = wsb + WP1OFF + (size_t)((c * 8 + kb) * 2) * 1024 + l * 16;
    } else {                               // Wp2 [10][256] -> 16x16 B-frags, cols 10..15 zero
        int kb = bid - 256;
        int a  = l & 15;
        int h0 = kb * 32 + ((l >> 4) & 3) * 8;
        if (a < 10) {
            const float* src = Wp2 + a * 256 + h0;
            fa = *(const float4*)src;
            fb = *(const float4*)(src + 4);
        }
        dst = wsb + WP2OFF + (size_t)(kb * 2) * 1024 + l * 16;
    }
    short8 hi, lo;
    split8(fa, fb, hi, lo);
    *(short8*)dst = hi;
    *(short8*)(dst + 1024) = lo;
}

// -------- main fused kernel: TWO batches per block, 8 waves (512 thr), 2 blocks/CU --------
// 8 waves -> 4 waves/SIMD (vs R11's 2): fills MFMA dependency-chain and LDS-latency
// gaps. Single-acc-per-wave keeps regs ~85 under the (512,4) 128-reg cap.
__global__ __launch_bounds__(512, 4)
void fused_net(const float* __restrict__ states, const uint8_t* __restrict__ wsb,
               float* __restrict__ out_policy, float* __restrict__ out_w1,
               float* __restrict__ out_w2) {
    __shared__ __align__(16) char smem[65536];

    const int b2   = blockIdx.x;       // batch pair index
    const int t    = threadIdx.x;
    const int w    = t >> 6;           // 0..7
    const int l    = t & 63;
    const int l31  = l & 31;
    const int half = l >> 5;
    const int l15  = l & 15;
    const int g4   = (l >> 4) & 3;
    const int rh   = w >> 2;           // row-half 0/1
    const int c4   = w & 3;            // col-tile 0..3

    // ---- stage 2 batches of X into hi/lo planes, coalesced ----
    {
        const float* src = states + (size_t)b2 * 8192;
#pragma unroll
        for (int r = 0; r < 4; ++r) {
            int flat = (t + 512 * r) * 4;
            int n = flat >> 7, d0 = flat & 127;    // n 0..63
            float4 v = *(const float4*)(src + flat);
            uint32_t b0 = __float_as_uint(v.x), b1 = __float_as_uint(v.y);
            uint32_t b2u = __float_as_uint(v.z), b3 = __float_as_uint(v.w);
            float r0 = v.x - __uint_as_float(b0 & 0xFFFF0000u);
            float r1 = v.y - __uint_as_float(b1 & 0xFFFF0000u);
            float r2 = v.z - __uint_as_float(b2u & 0xFFFF0000u);
            float r3 = v.w - __uint_as_float(b3 & 0xFFFF0000u);
            uint2 hw, lw;
            hw.x = __builtin_amdgcn_perm(b1, b0, 0x07060302u);
            hw.y = __builtin_amdgcn_perm(b3, b2u, 0x07060302u);
            lw.x = __builtin_amdgcn_perm(__float_as_uint(r1), __float_as_uint(r0), 0x07060302u);
            lw.y = __builtin_amdgcn_perm(__float_as_uint(r3), __float_as_uint(r2), 0x07060302u);
            *(uint2*)(smem + pl_addr(AH_OFF, n, d0)) = hw;
            *(uint2*)(smem + pl_addr(AL_OFF, n, d0)) = lw;
        }
    }
    __syncthreads();

#pragma unroll 1
    for (int blk = 0; blk < 2; ++blk) {
        const uint8_t* wb = wsb + (size_t)(blk * 3) * WSPROJ;

        // ---- projections: wave (rh,c4) owns one 32x32 tile of each of K, V, Q ----
        {
            f32x16 a = gemm32r(smem, wb + 0 * WSPROJ, rh * 32, c4, l);   // K
            store_plane32(smem, KB_OFF, rh * 32, c4, l, a);
        }
        __builtin_amdgcn_sched_barrier(0);
        {
            f32x16 a = gemm32r(smem, wb + 2 * WSPROJ, rh * 32, c4, l);   // V -> 1-term VT
            const int e = c4 * 32 + l31;
#pragma unroll
            for (int r = 0; r < 16; ++r) {
                int m = rh * 32 + (r & 3) + 8 * (r >> 2) + 4 * half;
                *(uint16_t*)(smem + vt_addr(e, m)) = f2bf_rne(a[r]);
            }
        }
        __builtin_amdgcn_sched_barrier(0);
        {
            f32x16 q = gemm32r(smem, wb + 1 * WSPROJ, rh * 32, c4, l);   // Q
            __syncthreads();                        // all X reads done; K/V visible
            store_plane32(smem, AL_OFF, rh * 32, c4, l, q);              // Q into dead X-lo
        }
        __builtin_amdgcn_sched_barrier(0);
        __syncthreads();                            // Q visible

        // ---- S = (Q K^T)*inv_scale: 8 16x16 tiles, one per wave ----
        {
            const int bq = w >> 2, rb = (w >> 1) & 1, mb = w & 1;
            const int qrow = bq * 32 + rb * 16 + l15;
            const int krow = bq * 32 + mb * 16 + l15;
            f32x4 s4 = {0.f, 0.f, 0.f, 0.f};
#pragma unroll
            for (int kb = 0; kb < 4; ++kb) {
                int e0 = kb * 32 + g4 * 8;
                U4 qh, kh;
                qh.q = *(const uint4*)(smem + pl_addr(AL_OFF, qrow, e0));
                kh.q = *(const uint4*)(smem + pl_addr(KB_OFF, krow, e0));
                s4 = __builtin_amdgcn_mfma_f32_16x16x32_bf16(qh.s8, kh.s8, s4, 0, 0, 0);
            }
            __syncthreads();                        // all K/Q reads done (S aliases KB)
#pragma unroll
            for (int r = 0; r < 4; ++r) {
                int n = bq * 32 + rb * 16 + g4 * 4 + r;    // verified 16x16 D mapping
                *(float*)(smem + s_addr(n, mb * 16 + l15)) = s4[r] * INV_SCALE;
            }
        }
        __syncthreads();

        // ---- softmax over m: 128 row-halves on waves 0-1 ----
        if (t < 128) {
            const int n = w * 32 + l31;            // w in {0,1} here
            float4 v0 = *(const float4*)(smem + s_addr(n, half * 16));
            float4 v1 = *(const float4*)(smem + s_addr(n, half * 16 + 4));
            float4 v2 = *(const float4*)(smem + s_addr(n, half * 16 + 8));
            float4 v3 = *(const float4*)(smem + s_addr(n, half * 16 + 12));
            float vv[16] = {v0.x, v0.y, v0.z, v0.w, v1.x, v1.y, v1.z, v1.w,
                            v2.x, v2.y, v2.z, v2.w, v3.x, v3.y, v3.z, v3.w};
            float mx = vv[0];
#pragma unroll
            for (int i = 1; i < 16; ++i) mx = fmaxf(mx, vv[i]);
            mx = fmaxf(mx, __shfl_xor(mx, 32));
            float sum = 0.f;
#pragma unroll
            for (int i = 0; i < 16; ++i) { vv[i] = __expf(vv[i] - mx); sum += vv[i]; }
            sum += __shfl_xor(sum, 32);
            float inv = 1.0f / sum;
#pragma unroll
            for (int i = 0; i < 16; ++i) vv[i] *= inv;
            *(float4*)(smem + s_addr(n, half * 16))      = make_float4(vv[0], vv[1], vv[2], vv[3]);
            *(float4*)(smem + s_addr(n, half * 16 + 4))  = make_float4(vv[4], vv[5], vv[6], vv[7]);
            *(float4*)(smem + s_addr(n, half * 16 + 8))  = make_float4(vv[8], vv[9], vv[10], vv[11]);
            *(float4*)(smem + s_addr(n, half * 16 + 12)) = make_float4(vv[12], vv[13], vv[14], vv[15]);
        }
        __syncthreads();

        // ---- attention-weight output for both batches (coalesced, 1 float4/thread) ----
        {
            float* outw = blk ? out_w2 : out_w1;
            int f = t * 4;                          // 0..2047
            int n = f >> 5, m0 = f & 31;
            float4 o = *(const float4*)(smem + s_addr(n, m0));
            *(float4*)(outw + (size_t)b2 * 2048 + f) = o;
        }

        // ---- PV: 8 tiles (bq, c4): ACT'[n][e] = sum_m P[n][m] V[m][e] ----
        {
            const int bq = w >> 2;
            f32x16 pv = {0.f,0.f,0.f,0.f, 0.f,0.f,0.f,0.f, 0.f,0.f,0.f,0.f, 0.f,0.f,0.f,0.f};
            const int e = c4 * 32 + l31;
#pragma unroll
            for (int kb = 0; kb < 2; ++kb) {
                int m0 = kb * 16 + half * 8;
                float4 fa = *(const float4*)(smem + s_addr(bq * 32 + l31, m0));
                float4 fb = *(const float4*)(smem + s_addr(bq * 32 + l31, m0 + 4));
                short8 wh, wl;
                split8(fa, fb, wh, wl);
                U4 vh;
                vh.q = *(const uint4*)(smem + vt_addr(e, bq * 32 + m0));
                pv = __builtin_amdgcn_mfma_f32_32x32x16_bf16(wh, vh.s8, pv, 0, 0, 0);
                pv = __builtin_amdgcn_mfma_f32_32x32x16_bf16(wl, vh.s8, pv, 0, 0, 0);
            }
            store_act32(smem, bq * 32, c4, l, pv);
        }
        __builtin_amdgcn_sched_barrier(0);
        __syncthreads();
    }

    // ---- MLP hidden: 16 tiles over 2 reps; H -> bf16 over dead KB+VT ----
#pragma unroll 1
    for (int rep = 0; rep < 2; ++rep) {
        const int hc = c4 + rep * 4;
        f32x16 a = gemm32r(smem, wsb + WP1OFF, rh * 32, hc, l);
        const int hcol = hc * 32 + l31;
#pragma unroll
        for (int r = 0; r < 16; ++r) {
            int n = rh * 32 + (r & 3) + 8 * (r >> 2) + 4 * half;
            float x = a[r];
            x = fmaxf(x, 0.01f * x);                // leaky_relu
            *(uint16_t*)(smem + h_addr(n, hcol)) = f2bf_rne(x);
        }
        __builtin_amdgcn_sched_barrier(0);
    }
    __syncthreads();

    // ---- policy logits: 4x 16x16 tiles (waves 0-3), K=256; logits -> dead AH ----
    if (w < 4) {
        f32x4 acc = {0.f, 0.f, 0.f, 0.f};
        const int n = w * 16 + l15;                 // rows 0..63
#pragma unroll
        for (int kb = 0; kb < 8; ++kb) {
            int h0 = kb * 32 + g4 * 8;
            U4 a;
            a.q = *(const uint4*)(smem + h_addr(n, h0));
            const uint8_t* p = wsb + WP2OFF + (size_t)(kb * 2) * 1024 + (size_t)l * 16;
            U4 bh, bl;
            bh.q = *(const uint4*)p;
            bl.q = *(const uint4*)(p + 1024);
            acc = __builtin_amdgcn_mfma_f32_16x16x32_bf16(a.s8, bh.s8, acc, 0, 0, 0);
            acc = __builtin_amdgcn_mfma_f32_16x16x32_bf16(a.s8, bl.s8, acc, 0, 0, 0);
        }
#pragma unroll
        for (int r = 0; r < 4; ++r) {
            int nn = w * 16 + g4 * 4 + r;
            *(float*)(smem + ps_addr(nn, l15)) = acc[r];
        }
    }
    __syncthreads();

    // ---- policy softmax over 10 actions (64 rows, wave 0) ----
    if (t < 64) {
        float v[10];
#pragma unroll
        for (int a2 = 0; a2 < 10; ++a2) v[a2] = *(const float*)(smem + ps_addr(t, a2));
        float mx = v[0];
#pragma unroll
        for (int a2 = 1; a2 < 10; ++a2) mx = fmaxf(mx, v[a2]);
        float sum = 0.f;
#pragma unroll
        for (int a2 = 0; a2 < 10; ++a2) { v[a2] = __expf(v[a2] - mx); sum += v[a2]; }
        float inv = 1.0f / sum;
#pragma unroll
        for (int a2 = 0; a2 < 10; ++a2) *(float*)(smem + ps_addr(t, a2)) = v[a2] * inv;
    }
    __syncthreads();

    for (int o = t; o < 640; o += 512) {
        int n = o / 10, a2 = o - n * 10;
        out_policy[(size_t)b2 * 640 + o] = *(const float*)(smem + ps_addr(n, a2));
    }
}

}  // namespace

extern "C" void kernel_launch(void* const* d_in, const int* in_sizes, int n_in,
                              void* d_out, int out_size, void* d_ws, size_t ws_size,
                              hipStream_t stream) {
    const float* states = (const float*)d_in[0];
    const float* Wk1 = (const float*)d_in[1];
    const float* Wq1 = (const float*)d_in[2];
    const float* Wv1 = (const float*)d_in[3];
    const float* Wk2 = (const float*)d_in[4];
    const float* Wq2 = (const float*)d_in[5];
    const float* Wv2 = (const float*)d_in[6];
    const float* Wp1 = (const float*)d_in[7];
    const float* Wp2 = (const float*)d_in[8];

    const int B = in_sizes[0] / 4096;   // 8192 batches

    uint8_t* wsb = (uint8_t*)d_ws;      // needs ~541 KB
    float* out        = (float*)d_out;
    float* out_policy = out;
    float* out_w1     = out_policy + (size_t)B * 320;
    float* out_w2     = out_w1 + (size_t)B * 1024;

    hipLaunchKernelGGL(prepack, dim3(264), dim3(64), 0, stream,
                       Wk1, Wq1, Wv1, Wk2, Wq2, Wv2, Wp1, Wp2, wsb);
    hipLaunchKernelGGL(fused_net, dim3(B / 2), dim3(512), 0, stream,
                       states, wsb, out_policy, out_w1, out_w2);
}